// Round 23
// baseline (398.082 us; speedup 1.0000x reference)
//
#include <hip/hip_runtime.h>
#include <hip/hip_bf16.h>

// N=100000, E=1600000.
// R23: encoder split into two halves; each half's shadow hides one serial
// stage. cxenc1 = count U encoder[0,50K) (1:1); xw1scan = xw1-MFMA U scan1;
// scatterenc2 = scatter U encoder[50K,100K) (1:1). Bodies identical to R22.

#define NEG_SLOPE 0.2f

using short8  = __attribute__((ext_vector_type(8))) short;
using floatx4 = __attribute__((ext_vector_type(4))) float;

__device__ __forceinline__ float bf_lo(unsigned u) { return __uint_as_float(u << 16); }
__device__ __forceinline__ float bf_hi(unsigned u) { return __uint_as_float(u & 0xffff0000u); }
__device__ __forceinline__ unsigned pk(float lo, float hi)
{
    __hip_bfloat16 l = __float2bfloat16(lo), h = __float2bfloat16(hi);
    unsigned ul = reinterpret_cast<unsigned short&>(l);
    unsigned uh = reinterpret_cast<unsigned short&>(h);
    return ul | (uh << 16);
}
__device__ __forceinline__ short bfs(float f)
{
    __hip_bfloat16 b = __float2bfloat16(f);
    return reinterpret_cast<short&>(b);
}

// ---------------------------------------------------------------------------
// Encoder block body: 8 nodes (eb*8 .. eb*8+7), 32 lanes/node, 12-fp32 K/V.
// Must be called by ALL 256 threads of the block (contains __syncthreads).
// ---------------------------------------------------------------------------
__device__ __forceinline__ void encoder_block(
    int eb, int t, float* sh,
    const float* __restrict__ Xf,
    const float* __restrict__ Wq, const float* __restrict__ bq,
    const float* __restrict__ Wk, const float* __restrict__ bk,
    const float* __restrict__ Wv, const float* __restrict__ bv,
    const float* __restrict__ g0, const float* __restrict__ be0,
    const float* __restrict__ Wf1, const float* __restrict__ bf1,
    const float* __restrict__ Wf2, const float* __restrict__ bf2,
    const float* __restrict__ g1, const float* __restrict__ be1,
    const float* __restrict__ Wrep, const float* __restrict__ brep,
    __hip_bfloat16* __restrict__ hx)
{
    size_t base = (size_t)eb * 2560;
#pragma unroll
    for (int i = 0; i < 10; ++i) sh[i * 256 + t] = Xf[base + i * 256 + t];
    __syncthreads();

    int sub = t >> 5;
    int s   = t & 31;
    int v   = eb * 8 + sub;

    float xv[10];
#pragma unroll
    for (int i = 0; i < 10; ++i) xv[i] = sh[sub * 320 + s * 10 + i];
    __syncthreads();   // Xf consumed; slab reused for K/V

    float q[6], k[6], w[6];
#pragma unroll
    for (int j = 0; j < 6; ++j) { q[j] = bq[j]; k[j] = bk[j]; w[j] = bv[j]; }
#pragma unroll
    for (int i = 0; i < 10; ++i) {
#pragma unroll
        for (int j = 0; j < 6; ++j) {
            q[j] += xv[i] * Wq[i * 6 + j];
            k[j] += xv[i] * Wk[i * 6 + j];
            w[j] += xv[i] * Wv[i * 6 + j];
        }
    }

    // K/V slab: 12 floats/token: [k0..k3][k4,k5,v0,v1][v2..v5]
    float* kv = sh + sub * 384;
    *(float4*)&kv[s * 12 + 0] = make_float4(k[0], k[1], k[2], k[3]);
    *(float4*)&kv[s * 12 + 4] = make_float4(k[4], k[5], w[0], w[1]);
    *(float4*)&kv[s * 12 + 8] = make_float4(w[2], w[3], w[4], w[5]);
    __builtin_amdgcn_wave_barrier();

    const float scale = 0.40824829046386301637f;  // 1/sqrt(6)
    float q0s = q[0] * scale, q1s = q[1] * scale, q2s = q[2] * scale;
    float q3s = q[3] * scale, q4s = q[4] * scale, q5s = q[5] * scale;

    float dA0 = 0.f, dB0 = 0.f, dA1 = 0.f, dB1 = 0.f;
    float aA00 = 0.f, aA01 = 0.f, aA02 = 0.f;
    float aB00 = 0.f, aB01 = 0.f, aB02 = 0.f;
    float aA10 = 0.f, aA11 = 0.f, aA12 = 0.f;
    float aB10 = 0.f, aB11 = 0.f, aB12 = 0.f;

#pragma unroll 4
    for (int t2 = 0; t2 < 32; t2 += 2) {
        float4 A0 = *(const float4*)&kv[t2 * 12 + 0];
        float4 A1 = *(const float4*)&kv[t2 * 12 + 4];
        float4 A2 = *(const float4*)&kv[t2 * 12 + 8];
        float4 B0 = *(const float4*)&kv[t2 * 12 + 12];
        float4 B1 = *(const float4*)&kv[t2 * 12 + 16];
        float4 B2 = *(const float4*)&kv[t2 * 12 + 20];
        {
            float p0 = __expf(q0s * A0.x + q1s * A0.y + q2s * A0.z);
            float p1 = __expf(q3s * A0.w + q4s * A1.x + q5s * A1.y);
            dA0 += p0; aA00 += p0 * A1.z; aA01 += p0 * A1.w; aA02 += p0 * A2.x;
            dA1 += p1; aA10 += p1 * A2.y; aA11 += p1 * A2.z; aA12 += p1 * A2.w;
        }
        {
            float p0 = __expf(q0s * B0.x + q1s * B0.y + q2s * B0.z);
            float p1 = __expf(q3s * B0.w + q4s * B1.x + q5s * B1.y);
            dB0 += p0; aB00 += p0 * B1.z; aB01 += p0 * B1.w; aB02 += p0 * B2.x;
            dB1 += p1; aB10 += p1 * B2.y; aB11 += p1 * B2.z; aB12 += p1 * B2.w;
        }
    }

    float O[6];
    {
        float inv0 = 1.f / (dA0 + dB0);
        float inv1 = 1.f / (dA1 + dB1);
        O[0] = q[0] + (aA00 + aB00) * inv0;
        O[1] = q[1] + (aA01 + aB01) * inv0;
        O[2] = q[2] + (aA02 + aB02) * inv0;
        O[3] = q[3] + (aA10 + aB10) * inv1;
        O[4] = q[4] + (aA11 + aB11) * inv1;
        O[5] = q[5] + (aA12 + aB12) * inv1;
    }

    // LayerNorm(g0, be0)
    {
        float mean = (O[0] + O[1] + O[2] + O[3] + O[4] + O[5]) * (1.f / 6.f);
        float var = 0.f;
#pragma unroll
        for (int j = 0; j < 6; ++j) { float d = O[j] - mean; var += d * d; }
        var *= (1.f / 6.f);
        float r = rsqrtf(var + 1e-5f);
#pragma unroll
        for (int j = 0; j < 6; ++j) O[j] = (O[j] - mean) * r * g0[j] + be0[j];
    }

    // streaming FFN 6->24->6 + residual
    float f[6];
#pragma unroll
    for (int j = 0; j < 6; ++j) f[j] = O[j] + bf2[j];
#pragma unroll 4
    for (int r = 0; r < 24; ++r) {
        float hr = bf1[r];
#pragma unroll
        for (int j = 0; j < 6; ++j) hr += O[j] * Wf1[j * 24 + r];
        hr = fmaxf(hr, 0.f);
#pragma unroll
        for (int j = 0; j < 6; ++j) f[j] += hr * Wf2[r * 6 + j];
    }
    // LayerNorm(g1, be1)
    {
        float mean = (f[0] + f[1] + f[2] + f[3] + f[4] + f[5]) * (1.f / 6.f);
        float var = 0.f;
#pragma unroll
        for (int j = 0; j < 6; ++j) { float d = f[j] - mean; var += d * d; }
        var *= (1.f / 6.f);
        float r = rsqrtf(var + 1e-5f);
#pragma unroll
        for (int j = 0; j < 6; ++j) f[j] = (f[j] - mean) * r * g1[j] + be1[j];
    }

    float wr = Wrep[s];
#pragma unroll
    for (int j = 0; j < 6; ++j) {
        float val = f[j] * wr;
#pragma unroll
        for (int off = 16; off >= 1; off >>= 1) val += __shfl_xor(val, off, 32);
        f[j] = val;
    }
    if (s == 0) {
        float br = brep[0];
#pragma unroll
        for (int j = 0; j < 6; ++j)
            hx[(size_t)v * 96 + 64 + j] = __float2bfloat16(f[j] + br);
    }
}

// ---------------------------------------------------------------------------
// prep: deg zeroing + W1extT (80x64) + W2extT (96x96) builds in one launch.
// ---------------------------------------------------------------------------
__global__ void __launch_bounds__(256) prep_kernel(
    const float* __restrict__ W1, const float* __restrict__ att1,
    __hip_bfloat16* __restrict__ w1t,
    const float* __restrict__ W2, const float* __restrict__ att2,
    __hip_bfloat16* __restrict__ w2t,
    int* __restrict__ deg, int n)
{
    int i = blockIdx.x * 256 + threadIdx.x;
    if (i < n) deg[i] = 0;
    if (i < 80 * 64) {
        int j = i / 64, k = i % 64;
        float val;
        if (j < 64) {
            val = W1[k * 64 + j];
        } else if (j < 72) {
            int h = j - 64;
            val = 0.f;
            for (int c = 0; c < 8; ++c)
                val += W1[k * 64 + h * 8 + c] * att1[h * 16 + c];
        } else {
            int h = j - 72;
            val = 0.f;
            for (int c = 0; c < 8; ++c)
                val += W1[k * 64 + h * 8 + c] * att1[h * 16 + 8 + c];
        }
        w1t[j * 64 + k] = __float2bfloat16(val);
    }
    if (i < 96 * 96) {
        int j = i / 96, k = i % 96;
        float val = 0.f;
        if (k < 70) {
            if (j < 80) {
                val = W2[k * 80 + j];
            } else if (j < 88) {
                int h = j - 80;
                for (int c = 0; c < 10; ++c)
                    val += W2[k * 80 + h * 10 + c] * att2[h * 20 + c];
            } else {
                int h = j - 88;
                for (int c = 0; c < 10; ++c)
                    val += W2[k * 80 + h * 10 + c] * att2[h * 20 + 10 + c];
            }
        }
        w2t[j * 96 + k] = __float2bfloat16(val);
    }
}

// ---------------------------------------------------------------------------
// cxenc1: count U encoder[0,ENC1) interleaved 1:1 (bid&1: 0=count, 1=enc).
// ---------------------------------------------------------------------------
__global__ void __launch_bounds__(256) cxenc1_kernel(
    const int* __restrict__ src, const int* __restrict__ dst,
    int* __restrict__ deg, int* __restrict__ rank, int e,
    const float* __restrict__ Xf,
    const float* __restrict__ Wq, const float* __restrict__ bq,
    const float* __restrict__ Wk, const float* __restrict__ bk,
    const float* __restrict__ Wv, const float* __restrict__ bv,
    const float* __restrict__ g0, const float* __restrict__ be0,
    const float* __restrict__ Wf1, const float* __restrict__ bf1,
    const float* __restrict__ Wf2, const float* __restrict__ bf2,
    const float* __restrict__ g1, const float* __restrict__ be1,
    const float* __restrict__ Wrep, const float* __restrict__ brep,
    __hip_bfloat16* __restrict__ hx)
{
    __shared__ float smem[3072];
    int t = threadIdx.x;
    int bid = blockIdx.x;
    if ((bid & 1) == 0) {
        int i = (bid >> 1) * 256 + t;
        if (i < e) {
            int ss = src[i], dd = dst[i];
            if (ss != dd) rank[i] = atomicAdd(&deg[dd], 1);
        }
    } else {
        encoder_block(bid >> 1, t, smem, Xf, Wq, bq, Wk, bk, Wv, bv,
                      g0, be0, Wf1, bf1, Wf2, bf2, g1, be1, Wrep, brep, hx);
    }
}

// ---------------------------------------------------------------------------
// xw1scan: [0,XB) xw1 MFMA | [XB,XB+NB) per-block deg sums (scan1).
// ---------------------------------------------------------------------------
__global__ void __launch_bounds__(256) xw1scan_kernel(
    const float* __restrict__ x, const __hip_bfloat16* __restrict__ w1t,
    __hip_bfloat16* __restrict__ xwb, float* __restrict__ ai,
    unsigned* __restrict__ ajp,
    const int* __restrict__ deg, int* __restrict__ bsum,
    int n, int XB)
{
    int t = threadIdx.x;
    int bid = blockIdx.x;

    if (bid < XB) {
        int wv = t >> 6, l = t & 63;
        int base = bid * 64 + wv * 16;
        if (base >= n) return;

        int mrow = l & 15;
        int kc   = (l >> 4) * 8;
        int dr0  = (l >> 4) * 4;

        const float* xr = x + (size_t)(base + mrow) * 64;
        short8 a0, a1;
#pragma unroll
        for (int i = 0; i < 8; ++i) {
            a0[i] = bfs(xr[kc + i]);
            a1[i] = bfs(xr[32 + kc + i]);
        }

        const short* wp = (const short*)w1t;

#pragma unroll
        for (int nt = 0; nt < 5; ++nt) {
            int col = nt * 16 + mrow;
            short8 b0 = *(const short8*)(wp + (size_t)col * 64 + kc);
            short8 b1 = *(const short8*)(wp + (size_t)col * 64 + 32 + kc);
            floatx4 acc = {0.f, 0.f, 0.f, 0.f};
            acc = __builtin_amdgcn_mfma_f32_16x16x32_bf16(a0, b0, acc, 0, 0, 0);
            acc = __builtin_amdgcn_mfma_f32_16x16x32_bf16(a1, b1, acc, 0, 0, 0);
            if (nt < 4) {
#pragma unroll
                for (int r = 0; r < 4; ++r) {
                    int m = base + dr0 + r;
                    xwb[(size_t)m * 64 + nt * 16 + mrow] =
                        __float2bfloat16(acc[r]);
                }
            } else {
#pragma unroll
                for (int r = 0; r < 4; ++r) {
                    int m = base + dr0 + r;
                    float val = acc[r];
                    float nb  = __shfl_xor(val, 1, 64);
                    if (mrow < 8) {
                        ai[(size_t)m * 8 + mrow] = val;
                    } else {
                        int h = mrow - 8;
                        if ((h & 1) == 0)
                            ajp[(size_t)m * 4 + (h >> 1)] = pk(val, nb);
                    }
                }
            }
        }
    } else {
        __shared__ int sh[256];
        int b = bid - XB;
        int base = b * 1024 + t * 4;
        int s = 0;
#pragma unroll
        for (int k = 0; k < 4; ++k)
            if (base + k < n) s += deg[base + k];
        sh[t] = s;
        __syncthreads();
        for (int off = 128; off >= 1; off >>= 1) {
            if (t < off) sh[t] += sh[t + off];
            __syncthreads();
        }
        if (t == 0) bsum[b] = sh[0];
    }
}

__global__ void __launch_bounds__(128) scan2_kernel(int* __restrict__ bsum, int nb)
{
    __shared__ int sh[128];
    int t = threadIdx.x;
    int v = (t < nb) ? bsum[t] : 0;
    sh[t] = v;
    __syncthreads();
    for (int off = 1; off < 128; off <<= 1) {
        int val = (t >= off) ? sh[t - off] : 0;
        __syncthreads();
        sh[t] += val;
        __syncthreads();
    }
    if (t < nb) bsum[t] = sh[t] - v;   // exclusive
}

__global__ void __launch_bounds__(1024) scan3_kernel(
    const int* __restrict__ deg, const int* __restrict__ bsum,
    int* __restrict__ offs, int n)
{
    __shared__ int sh[1024];
    int t = threadIdx.x;
    int i = blockIdx.x * 1024 + t;
    int v = (i < n) ? deg[i] : 0;
    sh[t] = v;
    __syncthreads();
    for (int off = 1; off < 1024; off <<= 1) {
        int val = (t >= off) ? sh[t - off] : 0;
        __syncthreads();
        sh[t] += val;
        __syncthreads();
    }
    if (i < n) offs[i] = bsum[blockIdx.x] + sh[t] - v;
}

// ---------------------------------------------------------------------------
// scatterenc2: scatter U encoder[ENC1,EB) interleaved 1:1.
// ---------------------------------------------------------------------------
__global__ void __launch_bounds__(256) scatterenc2_kernel(
    const int* __restrict__ src, const int* __restrict__ dst,
    const int* __restrict__ offsets, const int* __restrict__ rank,
    int* __restrict__ elist, int e,
    const float* __restrict__ Xf,
    const float* __restrict__ Wq, const float* __restrict__ bq,
    const float* __restrict__ Wk, const float* __restrict__ bk,
    const float* __restrict__ Wv, const float* __restrict__ bv,
    const float* __restrict__ g0, const float* __restrict__ be0,
    const float* __restrict__ Wf1, const float* __restrict__ bf1,
    const float* __restrict__ Wf2, const float* __restrict__ bf2,
    const float* __restrict__ g1, const float* __restrict__ be1,
    const float* __restrict__ Wrep, const float* __restrict__ brep,
    __hip_bfloat16* __restrict__ hx, int ENC1)
{
    __shared__ float smem[3072];
    int t = threadIdx.x;
    int bid = blockIdx.x;
    if ((bid & 1) == 0) {
        int i = (bid >> 1) * 256 + t;
        if (i < e) {
            int s = src[i], d = dst[i];
            if (s != d) elist[offsets[d] + rank[i]] = s;
        }
    } else {
        encoder_block(ENC1 + (bid >> 1), t, smem, Xf, Wq, bq, Wk, bk, Wv, bv,
                      g0, be0, Wf1, bf1, Wf2, bf2, g1, be1, Wrep, brep, hx);
    }
}

// ---------------------------------------------------------------------------
// GAT-1 aggregation, 8-edge chunks, two-phase. Writes hx cols 0..63 + pad.
// ---------------------------------------------------------------------------
__global__ void __launch_bounds__(256) agg1_kernel(
    const __hip_bfloat16* __restrict__ xwb, const float* __restrict__ ai1,
    const unsigned* __restrict__ ajp, const float* __restrict__ att1,
    const float* __restrict__ b1,
    const int* __restrict__ offs, const int* __restrict__ deg,
    const int* __restrict__ elist,
    __hip_bfloat16* __restrict__ hx, int n)
{
    int t = threadIdx.x, wv = t >> 6, l = t & 63;
    int v = blockIdx.x * 4 + wv;
    int h = l >> 3, c = l & 7;
    int e1 = l >> 3, hp = l & 7;

    float ai_l = ai1[(size_t)v * 8 + h];
    float ai_p = ai1[(size_t)v * 8 + hp];
    float attj_l = att1[h * 16 + 8 + c];

    float yself = __bfloat162float(xwb[(size_t)v * 64 + l]);
    float ps = yself * attj_l;
    ps += __shfl_xor(ps, 1, 64);
    ps += __shfl_xor(ps, 2, 64);
    ps += __shfl_xor(ps, 4, 64);
    float a = ai_l + ps;
    a = fmaxf(a, NEG_SLOPE * a);
    float ea  = __expf(a);
    float acc = ea * yself;

    float den_acc = 0.f;
    int off = offs[v], dg = deg[v];
    for (int j = 0; j < dg; j += 8) {
        int idxv = 0;
        if (l < 8 && j + l < dg) idxv = elist[off + j + l];
        int se = __shfl(idxv, e1, 64);
        unsigned aw = ajp[(size_t)se * 4 + (hp >> 1)];
        float ajv = (hp & 1) ? bf_hi(aw) : bf_lo(aw);
        float u = ai_p + ajv;
        u = fmaxf(u, NEG_SLOPE * u);
        float wl = __expf(u);
        wl = (j + e1 < dg) ? wl : 0.f;
        den_acc += wl;
#pragma unroll
        for (int b = 0; b < 8; ++b) {
            int s = __shfl(idxv, b, 64);
            float y = __bfloat162float(xwb[(size_t)s * 64 + l]);
            float w = __shfl(wl, b * 8 + h, 64);
            acc += w * y;
        }
    }
    den_acc += __shfl_xor(den_acc, 8, 64);
    den_acc += __shfl_xor(den_acc, 16, 64);
    den_acc += __shfl_xor(den_acc, 32, 64);
    float den = ea + __shfl(den_acc, h, 64);

    float o = acc / den + b1[l];
    o = o > 0.f ? o : expm1f(o);   // elu
    hx[(size_t)v * 96 + l] = __float2bfloat16(o);
    unsigned* rowu = (unsigned*)(hx + (size_t)v * 96);
    if (l < 13) rowu[35 + l] = 0u;   // zero-pad cols 70..95
}

// ---------------------------------------------------------------------------
// xw2 GEMM via MFMA: D[N x 96] = hx[N x 96] @ W2ext, 16 nodes per wave.
// ---------------------------------------------------------------------------
__global__ void __launch_bounds__(256) xw2mfma_kernel(
    const __hip_bfloat16* __restrict__ hx, const __hip_bfloat16* __restrict__ w2t,
    __hip_bfloat16* __restrict__ xw2p, float* __restrict__ ai2, int n)
{
    int t = threadIdx.x, wv = t >> 6, l = t & 63;
    int base = blockIdx.x * 64 + wv * 16;
    if (base >= n) return;

    int mrow = l & 15;
    int kc   = (l >> 4) * 8;
    int dr0  = (l >> 4) * 4;

    const short* hp = (const short*)hx;
    const short* wp = (const short*)w2t;

    short8 a0 = *(const short8*)(hp + (size_t)(base + mrow) * 96 + 0  + kc);
    short8 a1 = *(const short8*)(hp + (size_t)(base + mrow) * 96 + 32 + kc);
    short8 a2 = *(const short8*)(hp + (size_t)(base + mrow) * 96 + 64 + kc);

#pragma unroll
    for (int nt = 0; nt < 6; ++nt) {
        int col = nt * 16 + mrow;
        short8 b0 = *(const short8*)(wp + (size_t)col * 96 + 0  + kc);
        short8 b1 = *(const short8*)(wp + (size_t)col * 96 + 32 + kc);
        short8 b2 = *(const short8*)(wp + (size_t)col * 96 + 64 + kc);
        floatx4 acc = {0.f, 0.f, 0.f, 0.f};
        acc = __builtin_amdgcn_mfma_f32_16x16x32_bf16(a0, b0, acc, 0, 0, 0);
        acc = __builtin_amdgcn_mfma_f32_16x16x32_bf16(a1, b1, acc, 0, 0, 0);
        acc = __builtin_amdgcn_mfma_f32_16x16x32_bf16(a2, b2, acc, 0, 0, 0);
#pragma unroll
        for (int r = 0; r < 4; ++r) {
            int m = base + dr0 + r;
            float val = acc[r];
            if (nt < 5) {
                xw2p[(size_t)m * 128 + nt * 16 + mrow] = __float2bfloat16(val);
            } else {
                if (mrow < 8) ai2[(size_t)m * 8 + mrow] = val;
                else xw2p[(size_t)m * 128 + 80 + (mrow - 8)] = __float2bfloat16(val);
            }
        }
    }
}

// ---------------------------------------------------------------------------
// GAT-2 aggregation on packed rows, 8-edge chunks, two-phase.
// ---------------------------------------------------------------------------
__global__ void __launch_bounds__(256) agg2_kernel(
    const unsigned* __restrict__ xw2p, const float* __restrict__ ai2,
    const float* __restrict__ b2,
    const int* __restrict__ offs, const int* __restrict__ deg,
    const int* __restrict__ elist, float* __restrict__ out, int n)
{
    __shared__ float buf[4][80];
    __shared__ float buf2[4][10];
    int t = threadIdx.x, wv = t >> 6, l = t & 63;
    int v = blockIdx.x * 4 + wv;

    int hc = (l < 40) ? (l / 5) : 0;
    int e1 = l >> 3, hp = l & 7;
    float ai_p = ai2[(size_t)v * 8 + hp];
    float ai_l = (l < 40) ? ai2[(size_t)v * 8 + hc] : 0.f;

    bool act = l < 44;
    unsigned selfw = act ? xw2p[(size_t)v * 64 + l] : 0u;
    int ajl = 40 + (hc >> 1);
    unsigned ajw = __shfl(selfw, ajl, 64);
    float ajs = (hc & 1) ? bf_hi(ajw) : bf_lo(ajw);
    float a = ai_l + ajs;
    a = fmaxf(a, NEG_SLOPE * a);
    float e0 = __expf(a);
    float acc0 = e0 * bf_lo(selfw), acc1 = e0 * bf_hi(selfw);

    float den_acc = 0.f;
    int off = offs[v], dg = deg[v];
    for (int j = 0; j < dg; j += 8) {
        int idxv = 0;
        if (l < 8 && j + l < dg) idxv = elist[off + j + l];
        int se = __shfl(idxv, e1, 64);
        unsigned aw = xw2p[(size_t)se * 64 + 40 + (hp >> 1)];
        float ajv = (hp & 1) ? bf_hi(aw) : bf_lo(aw);
        float u = ai_p + ajv;
        u = fmaxf(u, NEG_SLOPE * u);
        float wl = __expf(u);
        wl = (j + e1 < dg) ? wl : 0.f;
        den_acc += wl;
#pragma unroll
        for (int b = 0; b < 8; ++b) {
            int s = __shfl(idxv, b, 64);
            unsigned yw = (l < 40) ? xw2p[(size_t)s * 64 + l] : 0u;
            float w = __shfl(wl, b * 8 + hc, 64);
            acc0 += w * bf_lo(yw);
            acc1 += w * bf_hi(yw);
        }
    }
    den_acc += __shfl_xor(den_acc, 8, 64);
    den_acc += __shfl_xor(den_acc, 16, 64);
    den_acc += __shfl_xor(den_acc, 32, 64);
    float den = e0 + __shfl(den_acc, hc, 64);

    if (l < 40) {
        float inv = 1.f / den;
        buf[wv][2 * l]     = acc0 * inv;
        buf[wv][2 * l + 1] = acc1 * inv;
    }
    __builtin_amdgcn_wave_barrier();
    if (l < 10) {
        float mval = 0.f;
#pragma unroll
        for (int hh = 0; hh < 8; ++hh) mval += buf[wv][hh * 10 + l];
        buf2[wv][l] = mval * 0.125f + b2[l];
    }
    __builtin_amdgcn_wave_barrier();
    if (l < 10) {
        float mx = -1e30f;
#pragma unroll
        for (int cc = 0; cc < 10; ++cc) mx = fmaxf(mx, buf2[wv][cc]);
        float se = 0.f;
#pragma unroll
        for (int cc = 0; cc < 10; ++cc) se += __expf(buf2[wv][cc] - mx);
        out[(size_t)v * 10 + l] = buf2[wv][l] - mx - __logf(se);
    }
}

// ---------------------------------------------------------------------------
extern "C" void kernel_launch(void* const* d_in, const int* in_sizes, int n_in,
                              void* d_out, int out_size, void* d_ws, size_t ws_size,
                              hipStream_t stream)
{
    const float* x    = (const float*)d_in[0];
    const int*   ei   = (const int*)  d_in[1];
    const float* ef   = (const float*)d_in[2];
    const float* W1   = (const float*)d_in[3];
    const float* att1 = (const float*)d_in[4];
    const float* b1   = (const float*)d_in[5];
    const float* W2   = (const float*)d_in[6];
    const float* att2 = (const float*)d_in[7];
    const float* b2   = (const float*)d_in[8];
    const float* Wq   = (const float*)d_in[9];
    const float* bq   = (const float*)d_in[10];
    const float* Wk   = (const float*)d_in[11];
    const float* bk   = (const float*)d_in[12];
    const float* Wv   = (const float*)d_in[13];
    const float* bv   = (const float*)d_in[14];
    const float* g0   = (const float*)d_in[15];
    const float* be0  = (const float*)d_in[16];
    const float* Wf1  = (const float*)d_in[17];
    const float* bf1  = (const float*)d_in[18];
    const float* Wf2  = (const float*)d_in[19];
    const float* bf2  = (const float*)d_in[20];
    const float* g1   = (const float*)d_in[21];
    const float* be1  = (const float*)d_in[22];
    const float* Wrep = (const float*)d_in[23];
    const float* brep = (const float*)d_in[24];

    const int n = in_sizes[0] / 64;   // 100000
    const int e = in_sizes[1] / 2;    // 1600000
    const int* src = ei;
    const int* dst = ei + e;

    char* ws = (char*)d_ws;
    size_t o = 0;
    auto alloc = [&](size_t bytes) -> void* {
        void* p = ws + o;
        o += (bytes + 255) & ~(size_t)255;
        return p;
    };
    __hip_bfloat16* xw1b = (__hip_bfloat16*)alloc((size_t)n * 64 * 2);
    __hip_bfloat16* hx   = (__hip_bfloat16*)alloc((size_t)n * 96 * 2);  // h1|xt|0
    __hip_bfloat16* xw2p = (__hip_bfloat16*)alloc((size_t)n * 128 * 2); // packed
    __hip_bfloat16* w2t  = (__hip_bfloat16*)alloc(96 * 96 * 2);
    __hip_bfloat16* w1t  = (__hip_bfloat16*)alloc(80 * 64 * 2);
    unsigned* ajp = (unsigned*)alloc((size_t)n * 4 * 4);  // packed bf16 aj1
    float* ai1   = (float*)alloc((size_t)n * 8 * 4);
    float* ai2   = (float*)alloc((size_t)n * 8 * 4);
    int*   deg   = (int*)  alloc((size_t)n * 4);
    int*   offs  = (int*)  alloc((size_t)n * 4);
    int*   rank  = (int*)  alloc((size_t)e * 4);
    int*   bsum  = (int*)  alloc(256 * 4);
    int*   elist = (int*)  alloc((size_t)e * 4);
    (void)ws_size; (void)n_in; (void)out_size;

    const int NB = (n + 1023) / 1024;    // 98 scan blocks
    const int EB = n / 8;                // 12500 encoder blocks total
    const int ENC1 = EB / 2;             // 6250 per half
    const int CB = (e + 255) / 256;      // 6250 count/scatter blocks
    const int XB = (n + 63) / 64;        // 1563 xw1-mfma blocks

    prep_kernel<<<(n + 255) / 256, 256, 0, stream>>>(W1, att1, w1t,
                                                     W2, att2, w2t, deg, n);
    // count U encoder first half (CB == ENC1 == 6250, 1:1 interleave)
    cxenc1_kernel<<<CB + ENC1, 256, 0, stream>>>(
        src, dst, deg, rank, e,
        ef, Wq, bq, Wk, bk, Wv, bv, g0, be0, Wf1, bf1, Wf2, bf2, g1, be1,
        Wrep, brep, hx);
    xw1scan_kernel<<<XB + NB, 256, 0, stream>>>(x, w1t, xw1b, ai1, ajp,
                                                deg, bsum, n, XB);
    scan2_kernel<<<1, 128, 0, stream>>>(bsum, NB);
    scan3_kernel<<<NB, 1024, 0, stream>>>(deg, bsum, offs, n);
    // scatter U encoder second half (1:1 interleave)
    scatterenc2_kernel<<<CB + ENC1, 256, 0, stream>>>(
        src, dst, offs, rank, elist, e,
        ef, Wq, bq, Wk, bk, Wv, bv, g0, be0, Wf1, bf1, Wf2, bf2, g1, be1,
        Wrep, brep, hx, ENC1);
    agg1_kernel<<<n / 4, 256, 0, stream>>>(xw1b, ai1, ajp, att1, b1,
                                           offs, deg, elist, hx, n);
    xw2mfma_kernel<<<(n + 63) / 64, 256, 0, stream>>>(hx, w2t, xw2p, ai2, n);
    agg2_kernel<<<n / 4, 256, 0, stream>>>((const unsigned*)xw2p, ai2, b2,
                                           offs, deg, elist, (float*)d_out, n);
}

// Round 24
// 359.897 us; speedup vs baseline: 1.1061x; 1.1061x over previous
//
#include <hip/hip_runtime.h>
#include <hip/hip_bf16.h>

// N=100000, E=1600000.
// R24: R22 schedule (best: 370us) with scan2 folded into scan3 (each scan3
// block reduces bsum[0..bid) itself; one fewer dependent launch).
// R23's encoder-split reverted (regressed: shadow doesn't subdivide).

#define NEG_SLOPE 0.2f

using short8  = __attribute__((ext_vector_type(8))) short;
using floatx4 = __attribute__((ext_vector_type(4))) float;

__device__ __forceinline__ float bf_lo(unsigned u) { return __uint_as_float(u << 16); }
__device__ __forceinline__ float bf_hi(unsigned u) { return __uint_as_float(u & 0xffff0000u); }
__device__ __forceinline__ unsigned pk(float lo, float hi)
{
    __hip_bfloat16 l = __float2bfloat16(lo), h = __float2bfloat16(hi);
    unsigned ul = reinterpret_cast<unsigned short&>(l);
    unsigned uh = reinterpret_cast<unsigned short&>(h);
    return ul | (uh << 16);
}
__device__ __forceinline__ short bfs(float f)
{
    __hip_bfloat16 b = __float2bfloat16(f);
    return reinterpret_cast<short&>(b);
}

// ---------------------------------------------------------------------------
// prep: deg zeroing + W1extT (80x64) + W2extT (96x96) builds in one launch.
// ---------------------------------------------------------------------------
__global__ void __launch_bounds__(256) prep_kernel(
    const float* __restrict__ W1, const float* __restrict__ att1,
    __hip_bfloat16* __restrict__ w1t,
    const float* __restrict__ W2, const float* __restrict__ att2,
    __hip_bfloat16* __restrict__ w2t,
    int* __restrict__ deg, int n)
{
    int i = blockIdx.x * 256 + threadIdx.x;
    if (i < n) deg[i] = 0;
    if (i < 80 * 64) {
        int j = i / 64, k = i % 64;
        float val;
        if (j < 64) {
            val = W1[k * 64 + j];
        } else if (j < 72) {
            int h = j - 64;
            val = 0.f;
            for (int c = 0; c < 8; ++c)
                val += W1[k * 64 + h * 8 + c] * att1[h * 16 + c];
        } else {
            int h = j - 72;
            val = 0.f;
            for (int c = 0; c < 8; ++c)
                val += W1[k * 64 + h * 8 + c] * att1[h * 16 + 8 + c];
        }
        w1t[j * 64 + k] = __float2bfloat16(val);
    }
    if (i < 96 * 96) {
        int j = i / 96, k = i % 96;
        float val = 0.f;
        if (k < 70) {
            if (j < 80) {
                val = W2[k * 80 + j];
            } else if (j < 88) {
                int h = j - 80;
                for (int c = 0; c < 10; ++c)
                    val += W2[k * 80 + h * 10 + c] * att2[h * 20 + c];
            } else {
                int h = j - 88;
                for (int c = 0; c < 10; ++c)
                    val += W2[k * 80 + h * 10 + c] * att2[h * 20 + 10 + c];
            }
        }
        w2t[j * 96 + k] = __float2bfloat16(val);
    }
}

// ---------------------------------------------------------------------------
// cx: [0,XB) xw1 MFMA | [XB,XB+CB) count. Independent halves.
// ---------------------------------------------------------------------------
__global__ void __launch_bounds__(256) cx_kernel(
    const float* __restrict__ x, const __hip_bfloat16* __restrict__ w1t,
    __hip_bfloat16* __restrict__ xwb, float* __restrict__ ai,
    unsigned* __restrict__ ajp,
    const int* __restrict__ src, const int* __restrict__ dst,
    int* __restrict__ deg, int* __restrict__ rank, int e,
    int n, int XB)
{
    int t = threadIdx.x;
    int bid = blockIdx.x;

    if (bid < XB) {
        int wv = t >> 6, l = t & 63;
        int base = bid * 64 + wv * 16;
        if (base >= n) return;

        int mrow = l & 15;
        int kc   = (l >> 4) * 8;
        int dr0  = (l >> 4) * 4;

        const float* xr = x + (size_t)(base + mrow) * 64;
        short8 a0, a1;
#pragma unroll
        for (int i = 0; i < 8; ++i) {
            a0[i] = bfs(xr[kc + i]);
            a1[i] = bfs(xr[32 + kc + i]);
        }

        const short* wp = (const short*)w1t;

#pragma unroll
        for (int nt = 0; nt < 5; ++nt) {
            int col = nt * 16 + mrow;
            short8 b0 = *(const short8*)(wp + (size_t)col * 64 + kc);
            short8 b1 = *(const short8*)(wp + (size_t)col * 64 + 32 + kc);
            floatx4 acc = {0.f, 0.f, 0.f, 0.f};
            acc = __builtin_amdgcn_mfma_f32_16x16x32_bf16(a0, b0, acc, 0, 0, 0);
            acc = __builtin_amdgcn_mfma_f32_16x16x32_bf16(a1, b1, acc, 0, 0, 0);
            if (nt < 4) {
#pragma unroll
                for (int r = 0; r < 4; ++r) {
                    int m = base + dr0 + r;
                    xwb[(size_t)m * 64 + nt * 16 + mrow] =
                        __float2bfloat16(acc[r]);
                }
            } else {
#pragma unroll
                for (int r = 0; r < 4; ++r) {
                    int m = base + dr0 + r;
                    float val = acc[r];
                    float nb  = __shfl_xor(val, 1, 64);
                    if (mrow < 8) {
                        ai[(size_t)m * 8 + mrow] = val;
                    } else {
                        int h = mrow - 8;
                        if ((h & 1) == 0)
                            ajp[(size_t)m * 4 + (h >> 1)] = pk(val, nb);
                    }
                }
            }
        }
    } else {
        int i = (bid - XB) * 256 + t;
        if (i < e) {
            int ss = src[i], dd = dst[i];
            if (ss != dd) rank[i] = atomicAdd(&deg[dd], 1);
        }
    }
}

// ---------------------------------------------------------------------------
// CSR build: scan1 (per-block sums) -> scan3 (self-prefixed) -> (scatterenc)
// ---------------------------------------------------------------------------
__global__ void __launch_bounds__(256) scan1_kernel(
    const int* __restrict__ deg, int* __restrict__ bsum, int n)
{
    __shared__ int sh[256];
    int t = threadIdx.x;
    int base = blockIdx.x * 1024 + t * 4;
    int s = 0;
#pragma unroll
    for (int k = 0; k < 4; ++k)
        if (base + k < n) s += deg[base + k];
    sh[t] = s;
    __syncthreads();
    for (int off = 128; off >= 1; off >>= 1) {
        if (t < off) sh[t] += sh[t + off];
        __syncthreads();
    }
    if (t == 0) bsum[blockIdx.x] = sh[0];
}

// scan3: per-element exclusive offsets; block prefix computed in-kernel by
// reducing bsum[0..bid) (nb <= 128).
__global__ void __launch_bounds__(1024) scan3_kernel(
    const int* __restrict__ deg, const int* __restrict__ bsum,
    int* __restrict__ offs, int n)
{
    __shared__ int sh[1024];
    __shared__ int pb[128];
    int t = threadIdx.x;
    int i = blockIdx.x * 1024 + t;
    int v = (i < n) ? deg[i] : 0;
    sh[t] = v;
    if (t < 128) pb[t] = (t < blockIdx.x) ? bsum[t] : 0;
    __syncthreads();
    for (int off = 64; off >= 1; off >>= 1) {
        if (t < off) pb[t] += pb[t + off];
        __syncthreads();
    }
    for (int off = 1; off < 1024; off <<= 1) {
        int val = (t >= off) ? sh[t - off] : 0;
        __syncthreads();
        sh[t] += val;
        __syncthreads();
    }
    if (i < n) offs[i] = pb[0] + sh[t] - v;
}

// ---------------------------------------------------------------------------
// scatterenc: scatter U encoder, interleaved 1:2 (bid%3==0 -> scatter).
// ---------------------------------------------------------------------------
__global__ void __launch_bounds__(256) scatterenc_kernel(
    // scatter
    const int* __restrict__ src, const int* __restrict__ dst,
    const int* __restrict__ offsets, const int* __restrict__ rank,
    int* __restrict__ elist, int e,
    // encoder
    const float* __restrict__ Xf,
    const float* __restrict__ Wq, const float* __restrict__ bq,
    const float* __restrict__ Wk, const float* __restrict__ bk,
    const float* __restrict__ Wv, const float* __restrict__ bv,
    const float* __restrict__ g0, const float* __restrict__ be0,
    const float* __restrict__ Wf1, const float* __restrict__ bf1,
    const float* __restrict__ Wf2, const float* __restrict__ bf2,
    const float* __restrict__ g1, const float* __restrict__ be1,
    const float* __restrict__ Wrep, const float* __restrict__ brep,
    __hip_bfloat16* __restrict__ hx,
    int n)
{
    __shared__ float smem[3072];
    int t = threadIdx.x;
    int bid = blockIdx.x;
    int sel = bid % 3;

    if (sel == 0) {
        // ------------------ scatter: 256 edges/block -----------------------
        int i = (bid / 3) * 256 + t;
        if (i < e) {
            int s = src[i], d = dst[i];
            if (s != d) elist[offsets[d] + rank[i]] = s;
        }
    } else {
        // ------------------ encoder: 8 nodes/block -------------------------
        int eb = (bid / 3) * 2 + (sel - 1);
        float* sh = smem;
        size_t base = (size_t)eb * 2560;
#pragma unroll
        for (int i = 0; i < 10; ++i) sh[i * 256 + t] = Xf[base + i * 256 + t];
        __syncthreads();

        int sub = t >> 5;
        int s   = t & 31;
        int v   = eb * 8 + sub;

        float xv[10];
#pragma unroll
        for (int i = 0; i < 10; ++i) xv[i] = sh[sub * 320 + s * 10 + i];
        __syncthreads();   // Xf consumed; slab reused for K/V

        float q[6], k[6], w[6];
#pragma unroll
        for (int j = 0; j < 6; ++j) { q[j] = bq[j]; k[j] = bk[j]; w[j] = bv[j]; }
#pragma unroll
        for (int i = 0; i < 10; ++i) {
#pragma unroll
            for (int j = 0; j < 6; ++j) {
                q[j] += xv[i] * Wq[i * 6 + j];
                k[j] += xv[i] * Wk[i * 6 + j];
                w[j] += xv[i] * Wv[i * 6 + j];
            }
        }

        // K/V slab: 12 floats/token: [k0..k3][k4,k5,v0,v1][v2..v5]
        float* kv = sh + sub * 384;
        *(float4*)&kv[s * 12 + 0] = make_float4(k[0], k[1], k[2], k[3]);
        *(float4*)&kv[s * 12 + 4] = make_float4(k[4], k[5], w[0], w[1]);
        *(float4*)&kv[s * 12 + 8] = make_float4(w[2], w[3], w[4], w[5]);
        __builtin_amdgcn_wave_barrier();

        const float scale = 0.40824829046386301637f;  // 1/sqrt(6)
        float q0s = q[0] * scale, q1s = q[1] * scale, q2s = q[2] * scale;
        float q3s = q[3] * scale, q4s = q[4] * scale, q5s = q[5] * scale;

        float dA0 = 0.f, dB0 = 0.f, dA1 = 0.f, dB1 = 0.f;
        float aA00 = 0.f, aA01 = 0.f, aA02 = 0.f;
        float aB00 = 0.f, aB01 = 0.f, aB02 = 0.f;
        float aA10 = 0.f, aA11 = 0.f, aA12 = 0.f;
        float aB10 = 0.f, aB11 = 0.f, aB12 = 0.f;

#pragma unroll 4
        for (int t2 = 0; t2 < 32; t2 += 2) {
            float4 A0 = *(const float4*)&kv[t2 * 12 + 0];
            float4 A1 = *(const float4*)&kv[t2 * 12 + 4];
            float4 A2 = *(const float4*)&kv[t2 * 12 + 8];
            float4 B0 = *(const float4*)&kv[t2 * 12 + 12];
            float4 B1 = *(const float4*)&kv[t2 * 12 + 16];
            float4 B2 = *(const float4*)&kv[t2 * 12 + 20];
            {
                float p0 = __expf(q0s * A0.x + q1s * A0.y + q2s * A0.z);
                float p1 = __expf(q3s * A0.w + q4s * A1.x + q5s * A1.y);
                dA0 += p0; aA00 += p0 * A1.z; aA01 += p0 * A1.w; aA02 += p0 * A2.x;
                dA1 += p1; aA10 += p1 * A2.y; aA11 += p1 * A2.z; aA12 += p1 * A2.w;
            }
            {
                float p0 = __expf(q0s * B0.x + q1s * B0.y + q2s * B0.z);
                float p1 = __expf(q3s * B0.w + q4s * B1.x + q5s * B1.y);
                dB0 += p0; aB00 += p0 * B1.z; aB01 += p0 * B1.w; aB02 += p0 * B2.x;
                dB1 += p1; aB10 += p1 * B2.y; aB11 += p1 * B2.z; aB12 += p1 * B2.w;
            }
        }

        float O[6];
        {
            float inv0 = 1.f / (dA0 + dB0);
            float inv1 = 1.f / (dA1 + dB1);
            O[0] = q[0] + (aA00 + aB00) * inv0;
            O[1] = q[1] + (aA01 + aB01) * inv0;
            O[2] = q[2] + (aA02 + aB02) * inv0;
            O[3] = q[3] + (aA10 + aB10) * inv1;
            O[4] = q[4] + (aA11 + aB11) * inv1;
            O[5] = q[5] + (aA12 + aB12) * inv1;
        }

        // LayerNorm(g0, be0)
        {
            float mean = (O[0] + O[1] + O[2] + O[3] + O[4] + O[5]) * (1.f / 6.f);
            float var = 0.f;
#pragma unroll
            for (int j = 0; j < 6; ++j) { float d = O[j] - mean; var += d * d; }
            var *= (1.f / 6.f);
            float r = rsqrtf(var + 1e-5f);
#pragma unroll
            for (int j = 0; j < 6; ++j) O[j] = (O[j] - mean) * r * g0[j] + be0[j];
        }

        // streaming FFN 6->24->6 + residual
        float f[6];
#pragma unroll
        for (int j = 0; j < 6; ++j) f[j] = O[j] + bf2[j];
#pragma unroll 4
        for (int r = 0; r < 24; ++r) {
            float hr = bf1[r];
#pragma unroll
            for (int j = 0; j < 6; ++j) hr += O[j] * Wf1[j * 24 + r];
            hr = fmaxf(hr, 0.f);
#pragma unroll
            for (int j = 0; j < 6; ++j) f[j] += hr * Wf2[r * 6 + j];
        }
        // LayerNorm(g1, be1)
        {
            float mean = (f[0] + f[1] + f[2] + f[3] + f[4] + f[5]) * (1.f / 6.f);
            float var = 0.f;
#pragma unroll
            for (int j = 0; j < 6; ++j) { float d = f[j] - mean; var += d * d; }
            var *= (1.f / 6.f);
            float r = rsqrtf(var + 1e-5f);
#pragma unroll
            for (int j = 0; j < 6; ++j) f[j] = (f[j] - mean) * r * g1[j] + be1[j];
        }

        float wr = Wrep[s];
#pragma unroll
        for (int j = 0; j < 6; ++j) {
            float val = f[j] * wr;
#pragma unroll
            for (int off = 16; off >= 1; off >>= 1) val += __shfl_xor(val, off, 32);
            f[j] = val;
        }
        if (s == 0) {
            float br = brep[0];
#pragma unroll
            for (int j = 0; j < 6; ++j)
                hx[(size_t)v * 96 + 64 + j] = __float2bfloat16(f[j] + br);
        }
    }
}

// ---------------------------------------------------------------------------
// GAT-1 aggregation, 8-edge chunks, two-phase. Writes hx cols 0..63 + pad.
// ---------------------------------------------------------------------------
__global__ void __launch_bounds__(256) agg1_kernel(
    const __hip_bfloat16* __restrict__ xwb, const float* __restrict__ ai1,
    const unsigned* __restrict__ ajp, const float* __restrict__ att1,
    const float* __restrict__ b1,
    const int* __restrict__ offs, const int* __restrict__ deg,
    const int* __restrict__ elist,
    __hip_bfloat16* __restrict__ hx, int n)
{
    int t = threadIdx.x, wv = t >> 6, l = t & 63;
    int v = blockIdx.x * 4 + wv;
    int h = l >> 3, c = l & 7;
    int e1 = l >> 3, hp = l & 7;

    float ai_l = ai1[(size_t)v * 8 + h];
    float ai_p = ai1[(size_t)v * 8 + hp];
    float attj_l = att1[h * 16 + 8 + c];

    float yself = __bfloat162float(xwb[(size_t)v * 64 + l]);
    float ps = yself * attj_l;
    ps += __shfl_xor(ps, 1, 64);
    ps += __shfl_xor(ps, 2, 64);
    ps += __shfl_xor(ps, 4, 64);
    float a = ai_l + ps;
    a = fmaxf(a, NEG_SLOPE * a);
    float ea  = __expf(a);
    float acc = ea * yself;

    float den_acc = 0.f;
    int off = offs[v], dg = deg[v];
    for (int j = 0; j < dg; j += 8) {
        int idxv = 0;
        if (l < 8 && j + l < dg) idxv = elist[off + j + l];
        int se = __shfl(idxv, e1, 64);
        unsigned aw = ajp[(size_t)se * 4 + (hp >> 1)];
        float ajv = (hp & 1) ? bf_hi(aw) : bf_lo(aw);
        float u = ai_p + ajv;
        u = fmaxf(u, NEG_SLOPE * u);
        float wl = __expf(u);
        wl = (j + e1 < dg) ? wl : 0.f;
        den_acc += wl;
#pragma unroll
        for (int b = 0; b < 8; ++b) {
            int s = __shfl(idxv, b, 64);
            float y = __bfloat162float(xwb[(size_t)s * 64 + l]);
            float w = __shfl(wl, b * 8 + h, 64);
            acc += w * y;
        }
    }
    den_acc += __shfl_xor(den_acc, 8, 64);
    den_acc += __shfl_xor(den_acc, 16, 64);
    den_acc += __shfl_xor(den_acc, 32, 64);
    float den = ea + __shfl(den_acc, h, 64);

    float o = acc / den + b1[l];
    o = o > 0.f ? o : expm1f(o);   // elu
    hx[(size_t)v * 96 + l] = __float2bfloat16(o);
    unsigned* rowu = (unsigned*)(hx + (size_t)v * 96);
    if (l < 13) rowu[35 + l] = 0u;   // zero-pad cols 70..95
}

// ---------------------------------------------------------------------------
// xw2 GEMM via MFMA: D[N x 96] = hx[N x 96] @ W2ext, 16 nodes per wave.
// ---------------------------------------------------------------------------
__global__ void __launch_bounds__(256) xw2mfma_kernel(
    const __hip_bfloat16* __restrict__ hx, const __hip_bfloat16* __restrict__ w2t,
    __hip_bfloat16* __restrict__ xw2p, float* __restrict__ ai2, int n)
{
    int t = threadIdx.x, wv = t >> 6, l = t & 63;
    int base = blockIdx.x * 64 + wv * 16;
    if (base >= n) return;

    int mrow = l & 15;
    int kc   = (l >> 4) * 8;
    int dr0  = (l >> 4) * 4;

    const short* hp = (const short*)hx;
    const short* wp = (const short*)w2t;

    short8 a0 = *(const short8*)(hp + (size_t)(base + mrow) * 96 + 0  + kc);
    short8 a1 = *(const short8*)(hp + (size_t)(base + mrow) * 96 + 32 + kc);
    short8 a2 = *(const short8*)(hp + (size_t)(base + mrow) * 96 + 64 + kc);

#pragma unroll
    for (int nt = 0; nt < 6; ++nt) {
        int col = nt * 16 + mrow;
        short8 b0 = *(const short8*)(wp + (size_t)col * 96 + 0  + kc);
        short8 b1 = *(const short8*)(wp + (size_t)col * 96 + 32 + kc);
        short8 b2 = *(const short8*)(wp + (size_t)col * 96 + 64 + kc);
        floatx4 acc = {0.f, 0.f, 0.f, 0.f};
        acc = __builtin_amdgcn_mfma_f32_16x16x32_bf16(a0, b0, acc, 0, 0, 0);
        acc = __builtin_amdgcn_mfma_f32_16x16x32_bf16(a1, b1, acc, 0, 0, 0);
        acc = __builtin_amdgcn_mfma_f32_16x16x32_bf16(a2, b2, acc, 0, 0, 0);
#pragma unroll
        for (int r = 0; r < 4; ++r) {
            int m = base + dr0 + r;
            float val = acc[r];
            if (nt < 5) {
                xw2p[(size_t)m * 128 + nt * 16 + mrow] = __float2bfloat16(val);
            } else {
                if (mrow < 8) ai2[(size_t)m * 8 + mrow] = val;
                else xw2p[(size_t)m * 128 + 80 + (mrow - 8)] = __float2bfloat16(val);
            }
        }
    }
}

// ---------------------------------------------------------------------------
// GAT-2 aggregation on packed rows, 8-edge chunks, two-phase.
// ---------------------------------------------------------------------------
__global__ void __launch_bounds__(256) agg2_kernel(
    const unsigned* __restrict__ xw2p, const float* __restrict__ ai2,
    const float* __restrict__ b2,
    const int* __restrict__ offs, const int* __restrict__ deg,
    const int* __restrict__ elist, float* __restrict__ out, int n)
{
    __shared__ float buf[4][80];
    __shared__ float buf2[4][10];
    int t = threadIdx.x, wv = t >> 6, l = t & 63;
    int v = blockIdx.x * 4 + wv;

    int hc = (l < 40) ? (l / 5) : 0;
    int e1 = l >> 3, hp = l & 7;
    float ai_p = ai2[(size_t)v * 8 + hp];
    float ai_l = (l < 40) ? ai2[(size_t)v * 8 + hc] : 0.f;

    bool act = l < 44;
    unsigned selfw = act ? xw2p[(size_t)v * 64 + l] : 0u;
    int ajl = 40 + (hc >> 1);
    unsigned ajw = __shfl(selfw, ajl, 64);
    float ajs = (hc & 1) ? bf_hi(ajw) : bf_lo(ajw);
    float a = ai_l + ajs;
    a = fmaxf(a, NEG_SLOPE * a);
    float e0 = __expf(a);
    float acc0 = e0 * bf_lo(selfw), acc1 = e0 * bf_hi(selfw);

    float den_acc = 0.f;
    int off = offs[v], dg = deg[v];
    for (int j = 0; j < dg; j += 8) {
        int idxv = 0;
        if (l < 8 && j + l < dg) idxv = elist[off + j + l];
        int se = __shfl(idxv, e1, 64);
        unsigned aw = xw2p[(size_t)se * 64 + 40 + (hp >> 1)];
        float ajv = (hp & 1) ? bf_hi(aw) : bf_lo(aw);
        float u = ai_p + ajv;
        u = fmaxf(u, NEG_SLOPE * u);
        float wl = __expf(u);
        wl = (j + e1 < dg) ? wl : 0.f;
        den_acc += wl;
#pragma unroll
        for (int b = 0; b < 8; ++b) {
            int s = __shfl(idxv, b, 64);
            unsigned yw = (l < 40) ? xw2p[(size_t)s * 64 + l] : 0u;
            float w = __shfl(wl, b * 8 + hc, 64);
            acc0 += w * bf_lo(yw);
            acc1 += w * bf_hi(yw);
        }
    }
    den_acc += __shfl_xor(den_acc, 8, 64);
    den_acc += __shfl_xor(den_acc, 16, 64);
    den_acc += __shfl_xor(den_acc, 32, 64);
    float den = e0 + __shfl(den_acc, hc, 64);

    if (l < 40) {
        float inv = 1.f / den;
        buf[wv][2 * l]     = acc0 * inv;
        buf[wv][2 * l + 1] = acc1 * inv;
    }
    __builtin_amdgcn_wave_barrier();
    if (l < 10) {
        float mval = 0.f;
#pragma unroll
        for (int hh = 0; hh < 8; ++hh) mval += buf[wv][hh * 10 + l];
        buf2[wv][l] = mval * 0.125f + b2[l];
    }
    __builtin_amdgcn_wave_barrier();
    if (l < 10) {
        float mx = -1e30f;
#pragma unroll
        for (int cc = 0; cc < 10; ++cc) mx = fmaxf(mx, buf2[wv][cc]);
        float se = 0.f;
#pragma unroll
        for (int cc = 0; cc < 10; ++cc) se += __expf(buf2[wv][cc] - mx);
        out[(size_t)v * 10 + l] = buf2[wv][l] - mx - __logf(se);
    }
}

// ---------------------------------------------------------------------------
extern "C" void kernel_launch(void* const* d_in, const int* in_sizes, int n_in,
                              void* d_out, int out_size, void* d_ws, size_t ws_size,
                              hipStream_t stream)
{
    const float* x    = (const float*)d_in[0];
    const int*   ei   = (const int*)  d_in[1];
    const float* ef   = (const float*)d_in[2];
    const float* W1   = (const float*)d_in[3];
    const float* att1 = (const float*)d_in[4];
    const float* b1   = (const float*)d_in[5];
    const float* W2   = (const float*)d_in[6];
    const float* att2 = (const float*)d_in[7];
    const float* b2   = (const float*)d_in[8];
    const float* Wq   = (const float*)d_in[9];
    const float* bq   = (const float*)d_in[10];
    const float* Wk   = (const float*)d_in[11];
    const float* bk   = (const float*)d_in[12];
    const float* Wv   = (const float*)d_in[13];
    const float* bv   = (const float*)d_in[14];
    const float* g0   = (const float*)d_in[15];
    const float* be0  = (const float*)d_in[16];
    const float* Wf1  = (const float*)d_in[17];
    const float* bf1  = (const float*)d_in[18];
    const float* Wf2  = (const float*)d_in[19];
    const float* bf2  = (const float*)d_in[20];
    const float* g1   = (const float*)d_in[21];
    const float* be1  = (const float*)d_in[22];
    const float* Wrep = (const float*)d_in[23];
    const float* brep = (const float*)d_in[24];

    const int n = in_sizes[0] / 64;   // 100000
    const int e = in_sizes[1] / 2;    // 1600000
    const int* src = ei;
    const int* dst = ei + e;

    char* ws = (char*)d_ws;
    size_t o = 0;
    auto alloc = [&](size_t bytes) -> void* {
        void* p = ws + o;
        o += (bytes + 255) & ~(size_t)255;
        return p;
    };
    __hip_bfloat16* xw1b = (__hip_bfloat16*)alloc((size_t)n * 64 * 2);
    __hip_bfloat16* hx   = (__hip_bfloat16*)alloc((size_t)n * 96 * 2);  // h1|xt|0
    __hip_bfloat16* xw2p = (__hip_bfloat16*)alloc((size_t)n * 128 * 2); // packed
    __hip_bfloat16* w2t  = (__hip_bfloat16*)alloc(96 * 96 * 2);
    __hip_bfloat16* w1t  = (__hip_bfloat16*)alloc(80 * 64 * 2);
    unsigned* ajp = (unsigned*)alloc((size_t)n * 4 * 4);  // packed bf16 aj1
    float* ai1   = (float*)alloc((size_t)n * 8 * 4);
    float* ai2   = (float*)alloc((size_t)n * 8 * 4);
    int*   deg   = (int*)  alloc((size_t)n * 4);
    int*   offs  = (int*)  alloc((size_t)n * 4);
    int*   rank  = (int*)  alloc((size_t)e * 4);
    int*   bsum  = (int*)  alloc(256 * 4);
    int*   elist = (int*)  alloc((size_t)e * 4);
    (void)ws_size; (void)n_in; (void)out_size;

    const int NB = (n + 1023) / 1024;    // 98 scan blocks
    const int CB = (e + 255) / 256;      // 6250 count/scatter blocks
    const int XB = (n + 63) / 64;        // 1563 xw1-mfma blocks

    prep_kernel<<<(n + 255) / 256, 256, 0, stream>>>(W1, att1, w1t,
                                                     W2, att2, w2t, deg, n);
    cx_kernel<<<XB + CB, 256, 0, stream>>>(x, w1t, xw1b, ai1, ajp,
                                           src, dst, deg, rank, e, n, XB);
    scan1_kernel<<<NB, 256, 0, stream>>>(deg, bsum, n);
    scan3_kernel<<<NB, 1024, 0, stream>>>(deg, bsum, offs, n);
    // scatter U encoder: 1:2 interleave; CB == EB/2 exactly (6250 vs 12500)
    scatterenc_kernel<<<CB * 3, 256, 0, stream>>>(
        src, dst, offs, rank, elist, e,
        ef, Wq, bq, Wk, bk, Wv, bv, g0, be0, Wf1, bf1, Wf2, bf2, g1, be1,
        Wrep, brep, hx, n);
    agg1_kernel<<<n / 4, 256, 0, stream>>>(xw1b, ai1, ajp, att1, b1,
                                           offs, deg, elist, hx, n);
    xw2mfma_kernel<<<(n + 63) / 64, 256, 0, stream>>>(hx, w2t, xw2p, ai2, n);
    agg2_kernel<<<n / 4, 256, 0, stream>>>((const unsigned*)xw2p, ai2, b2,
                                           offs, deg, elist, (float*)d_out, n);
}